// Round 4
// baseline (106.537 us; speedup 1.0000x reference)
//
#include <hip/hip_runtime.h>

#define KSZ   121
#define KMEAN 60
#define IMW   512
#define IMH   512
#define NPLANES 24            // 8 * 3
#define NROWS (NPLANES * IMH) // 12288 independent image rows
#define TK    640             // padded k-extent of tmp^T (64 | 512 | 64)
#define TPAD  64

typedef float    f32x4 __attribute__((ext_vector_type(4)));
typedef _Float16 f16x8 __attribute__((ext_vector_type(8)));
typedef _Float16 f16x4 __attribute__((ext_vector_type(4)));

// ---------------------------------------------------------------------------
// ws layout (bytes):
//   [    0,  512)  taps w[0..120] fp32 (pad to 128 with 0)
//   [  512, 2560)  L[512] fp32   (float idx 128..640)
//   [ 2560, 4608)  R[512] fp32   (float idx 640..1152)
//   [ 4608,14848)  10 MFMA weight-band tables, fp16, fragment order:
//                    T[tt][lane][j], tt = tau+1, tau in [-1,8]
//                    value = w[16*tau + kk - ci - 4], kk = 8*(lane>>4)+j,
//                    ci = lane&15; 0 outside [0,120].
//   [16384, ... )  fp16 tmp^T: [plane][col][TK], k stored at entry k+64;
//                  entries [0,64) and [576,640) are ZEROED pads (vertical
//                  zero-pad becomes plain in-bounds loads of 0.0).
//
// Banded-matmul identity shared by BOTH passes (w-idx = 16(2s-n)+kk-ci-4):
//   h-pass:  A = x rows (i=out-row), B = table (j=out-col), tau = 2s-n
//   v-pass:  A = table (i=out-row),  B = tmpT  (j=out-col), tau = 2s-n
// Validated end-to-end in rounds 1-2; this round only changes tmp layout
// (transposed+padded) and load/store shapes, not the algebra.
// ---------------------------------------------------------------------------
__global__ __launch_bounds__(128) void weights_kernel(const float* __restrict__ sigma,
                                                      float* __restrict__ ws) {
    __shared__ float w[121];
    __shared__ float P[121];
    int t = threadIdx.x;
    float s = sigma[0] * 8.0f + 16.0f;
    float ninv = -1.0f / (2.0f * s * s);
    if (t < 121) { float d = (float)(t - KMEAN); w[t] = __expf(d * d * ninv); }
    __syncthreads();
    if (t == 0) {
        float sum = 0.f;
        for (int i = 0; i < 121; ++i) sum += w[i];
        float inv = 1.f / sum, run = 0.f;
        for (int i = 0; i < 121; ++i) { float wi = w[i] * inv; w[i] = wi; run += wi; P[i] = run; }
    }
    __syncthreads();
    ws[t] = (t < 121) ? w[t] : 0.f;                       // taps, 121..127 = 0
    #pragma unroll
    for (int j = 0; j < 4; ++j) {
        int o = t * 4 + j;
        ws[128 + o] = (o <= 59)  ? P[59 - o]          : 0.f;   // L
        ws[640 + o] = (o >= 452) ? (1.f - P[571 - o]) : 0.f;   // R
    }
    // MFMA band tables (fp16, fragment order). 10 tables x 512 entries.
    _Float16* tab = (_Float16*)((char*)ws + 4608);
    #pragma unroll
    for (int tt = 0; tt < 10; ++tt) {
        for (int e = t; e < 512; e += 128) {
            int lane = e >> 3, j = e & 7;
            int kk = ((lane >> 4) << 3) + j;   // slot->k convention (shared A/B)
            int ci = lane & 15;
            int wi = 16 * (tt - 1) + kk - ci - 4;
            float v = (wi >= 0 && wi <= 120) ? w[wi] : 0.f;
            tab[tt * 512 + e] = (_Float16)v;
        }
    }
}

// ---------------------------------------------------------------------------
// hblur step body, shape-specialized (S0..S1-1 are the valid 32-col K-steps).
// Straight-line + 2-deep load pipeline: loads of step s+1 issue before the
// MFMAs of step s (no runtime branch blocks hoisting).
// ---------------------------------------------------------------------------
template<int S0, int S1>
__device__ __forceinline__ void hsteps(const float* __restrict__ xr0,
                                       const float* __restrict__ xr1,
                                       int c0, int g,
                                       const f16x8 (&T)[10],
                                       f32x4 (&acc)[2][4]) {
    f32x4 u0[2], u1[2], v0[2], v1[2];
#define HLOAD(S, B) do { const int co_ = c0 - 64 + 32 * (S) + 8 * g;          \
        u0[B] = *(const f32x4*)(xr0 + co_);                                   \
        u1[B] = *(const f32x4*)(xr0 + co_ + 4);                               \
        v0[B] = *(const f32x4*)(xr1 + co_);                                   \
        v1[B] = *(const f32x4*)(xr1 + co_ + 4); } while (0)
    HLOAD(S0, S0 & 1);
    #pragma unroll
    for (int s = S0; s < S1; ++s) {
        if (s + 1 < S1) HLOAD(s + 1, (s + 1) & 1);
        const int b = s & 1;
        f16x8 A0, A1;
        A0[0]=(_Float16)u0[b].x; A0[1]=(_Float16)u0[b].y; A0[2]=(_Float16)u0[b].z; A0[3]=(_Float16)u0[b].w;
        A0[4]=(_Float16)u1[b].x; A0[5]=(_Float16)u1[b].y; A0[6]=(_Float16)u1[b].z; A0[7]=(_Float16)u1[b].w;
        A1[0]=(_Float16)v0[b].x; A1[1]=(_Float16)v0[b].y; A1[2]=(_Float16)v0[b].z; A1[3]=(_Float16)v0[b].w;
        A1[4]=(_Float16)v1[b].x; A1[5]=(_Float16)v1[b].y; A1[6]=(_Float16)v1[b].z; A1[7]=(_Float16)v1[b].w;
        #pragma unroll
        for (int n = 0; n < 4; ++n) {
            const int tt = 2 * s - n + 1;              // tau+1, compile-time
            if (tt >= 0 && tt < 10) {
                acc[0][n] = __builtin_amdgcn_mfma_f32_16x16x32_f16(A0, T[tt], acc[0][n], 0, 0, 0);
                acc[1][n] = __builtin_amdgcn_mfma_f32_16x16x32_f16(A1, T[tt], acc[1][n], 0, 0, 0);
            }
        }
    }
#undef HLOAD
}

// ---------------------------------------------------------------------------
// Kernel 2: horizontal pass, banded f16 MFMA (algebra from round 1).
// Changes this round: (a) per-step runtime branch -> 3 compile-time shapes,
// (b) output stored TRANSPOSED + k-padded: tmpT[plane][col][TK], reg-quad
// r=0..3 (D rows 4g+r) packs to one f16x4 8B store (16 segs x 32B / inst),
// (c) br%4==0 blocks also zero the k-pads for their (plane, col-tile).
// ---------------------------------------------------------------------------
__global__ __launch_bounds__(256) void hblur_mfma(const float* __restrict__ x,
                                                  const float* __restrict__ ws,
                                                  _Float16* __restrict__ tmpT) {
    // XCD-aware swizzle: 768 blocks % 8 == 0; consecutive swz share x-windows.
    const int bid = blockIdx.x;
    const int swz = (bid & 7) * 96 + (bid >> 3);
    const int br = swz >> 3;                 // 0..95  row-block (128 rows)
    const int bc = swz & 7;                  // 0..7   col-tile (64 cols)
    const int tid  = threadIdx.x;
    const int lane = tid & 63;
    const int g    = lane >> 4;              // k-block / D-row group
    const int ci   = lane & 15;              // A row within tile / D col
    const int wq   = tid >> 6;
    const int R0   = br * 128 + wq * 32;
    const int c0   = bc * 64;
    const int plane = br >> 2;               // 4 row-blocks per 512-row plane
    const int rp0   = (br & 3) * 128 + wq * 32;   // row base within plane

    // preload the 10 band tables (wave-uniform B fragments)
    const _Float16* __restrict__ tab = (const _Float16*)((const char*)ws + 4608);
    f16x8 T[10];
    #pragma unroll
    for (int tt = 0; tt < 10; ++tt)
        T[tt] = ((const f16x8*)(tab + tt * 512))[lane];

    f32x4 acc[2][4];
    #pragma unroll
    for (int q = 0; q < 2; ++q)
        #pragma unroll
        for (int n = 0; n < 4; ++n)
            acc[q][n] = (f32x4){0.f, 0.f, 0.f, 0.f};

    const float* __restrict__ xr0 = x + (size_t)(R0 + ci) * IMW;        // q=0 row
    const float* __restrict__ xr1 = x + (size_t)(R0 + 16 + ci) * IMW;   // q=1 row

    // shape dispatch: skipped steps are exactly those with colbase outside
    // [0,512) (identical to rounds 1-2's runtime check, now compile-time)
    if (c0 == 0)        hsteps<2, 6>(xr0, xr1, c0, g, T, acc);
    else if (c0 == 448) hsteps<0, 4>(xr0, xr1, c0, g, T, acc);
    else                hsteps<0, 6>(xr0, xr1, c0, g, T, acc);

    // replicate-pad corrections, only the two edge col-tiles have nonzero L/R
    if (c0 == 0 || c0 == 448) {
        const float* __restrict__ Lf = ws + 128;
        const float* __restrict__ Rf = ws + 640;
        float Lc[4], Rc[4];
        #pragma unroll
        for (int n = 0; n < 4; ++n) {
            Lc[n] = Lf[c0 + 16 * n + ci];
            Rc[n] = Rf[c0 + 16 * n + ci];
        }
        #pragma unroll
        for (int q = 0; q < 2; ++q) {
            #pragma unroll
            for (int r = 0; r < 4; ++r) {
                const int row = R0 + 16 * q + 4 * g + r;   // D row = 4g+reg
                const float x0 = x[(size_t)row * IMW];
                const float xN = x[(size_t)row * IMW + IMW - 1];
                #pragma unroll
                for (int n = 0; n < 4; ++n)
                    acc[q][n][r] += x0 * Lc[n] + xN * Rc[n];
            }
        }
    }

    // transposed packed store: tmpT[plane][col][64 + rowInPlane], the D-reg
    // quad (rows 4g+0..3 of col c0+16n+ci) is 4 consecutive k entries = 8B.
    _Float16* __restrict__ tq = tmpT + (size_t)plane * (IMW * TK);
    #pragma unroll
    for (int q = 0; q < 2; ++q)
        #pragma unroll
        for (int n = 0; n < 4; ++n) {
            f16x4 pk;
            pk[0] = (_Float16)acc[q][n][0];
            pk[1] = (_Float16)acc[q][n][1];
            pk[2] = (_Float16)acc[q][n][2];
            pk[3] = (_Float16)acc[q][n][3];
            *(f16x4*)(tq + (size_t)(c0 + 16 * n + ci) * TK
                         + TPAD + rp0 + 16 * q + 4 * g) = pk;
        }

    // zero the k-pads for this (plane, col-tile): entries [0,64) and [576,640)
    // of each of the 64 cols. 256 threads x 4 x f16x8 stores = 16 KB.
    if ((br & 3) == 0) {
        const int col  = c0 + (tid >> 2);
        const int part = tid & 3;
        _Float16* __restrict__ pz = tq + (size_t)col * TK
                                       + ((part < 2) ? part * 32 : 576 + (part - 2) * 32);
        const f16x8 z = (f16x8){0, 0, 0, 0, 0, 0, 0, 0};
        #pragma unroll
        for (int i = 0; i < 4; ++i)
            *(f16x8*)(pz + 8 * i) = z;
    }
}

// ---------------------------------------------------------------------------
// Kernel 3: vertical pass, banded f16 MFMA on transposed tmp.
//   out[r,c] = sum_k w[k-r+60]*tmp[k,c] + L[r]*tmp[0,c] + R[r]*tmp[511,c]
// A = band tables (i = out-row = lane&15). B = tmpT fragments: k-slots are
// CONTIGUOUS in tmpT -> one 16B f16x8 load per fragment (was 8 u16 loads +
// packs). k<0 / k>=512 hit the zeroed pads -> branchless, no SRD anywhere.
// Wave tile: 64 rows (n) x 32 cols (m=0,1). Block = 4 waves = 64r x 128c.
// 2-deep load pipeline over the 6 K-steps.
// ---------------------------------------------------------------------------
__global__ __launch_bounds__(256) void vblur_mfma(const _Float16* __restrict__ tmpT,
                                                  const float* __restrict__ ws,
                                                  float* __restrict__ out) {
    const int bid = blockIdx.x;
    const int swz = (bid & 7) * 96 + (bid >> 3);   // 768 = 8 * 96, bijective
    const int rb  = swz >> 2;                      // 0..191: 64-row block
    const int cbw = swz & 3;                       // 0..3: 128-col block
    const int tid  = threadIdx.x;
    const int lane = tid & 63;
    const int wv   = tid >> 6;                     // wave -> 32-col tile
    const int g    = lane >> 4;
    const int ci   = lane & 15;
    const int plane = rb >> 3;
    const int r0p   = (rb & 7) * 64;               // row base within plane
    const int cw    = cbw * 128 + wv * 32;

    const _Float16* __restrict__ tq  = tmpT + (size_t)plane * (IMW * TK);
    const _Float16* __restrict__ bp0 = tq + (size_t)(cw + ci) * TK;   // m=0 col
    const _Float16* __restrict__ bp1 = bp0 + 16 * TK;                 // m=1 col
    float* __restrict__ op = out + (size_t)plane * (IMW * IMH);

    // preload the 10 band tables as A-operands (lane&15 = out-row, slots = k)
    const _Float16* __restrict__ tab = (const _Float16*)((const char*)ws + 4608);
    f16x8 T[10];
    #pragma unroll
    for (int tt = 0; tt < 10; ++tt)
        T[tt] = ((const f16x8*)(tab + tt * 512))[lane];

    f32x4 acc[4][2];
    #pragma unroll
    for (int n = 0; n < 4; ++n) {
        acc[n][0] = (f32x4){0.f, 0.f, 0.f, 0.f};
        acc[n][1] = (f32x4){0.f, 0.f, 0.f, 0.f};
    }

    // B fragment entry index: TPAD + (r0p-64+32s) + 8g = r0p + 32s + 8g >= 0,
    // max = 448 + 160 + 24 + 7 = 639 < TK: always in-bounds, pads supply 0.
    f16x8 B0[2], B1[2];
#define VLOAD(S, B) do { const int e_ = r0p + 32 * (S) + 8 * g;               \
        B0[B] = *(const f16x8*)(bp0 + e_);                                    \
        B1[B] = *(const f16x8*)(bp1 + e_); } while (0)
    VLOAD(0, 0);
    #pragma unroll
    for (int s = 0; s < 6; ++s) {
        if (s < 5) VLOAD(s + 1, (s + 1) & 1);
        const int b = s & 1;
        #pragma unroll
        for (int n = 0; n < 4; ++n) {
            const int tt = 2 * s - n + 1;              // tau+1, compile-time
            if (tt >= 0 && tt < 10) {
                acc[n][0] = __builtin_amdgcn_mfma_f32_16x16x32_f16(T[tt], B0[b], acc[n][0], 0, 0, 0);
                acc[n][1] = __builtin_amdgcn_mfma_f32_16x16x32_f16(T[tt], B1[b], acc[n][1], 0, 0, 0);
            }
        }
    }
#undef VLOAD

    // replicate-pad corrections: tmp rows 0/511 = tmpT entries TPAD/TPAD+511
    if (r0p == 0 || r0p == 448) {
        const float* __restrict__ Lf = ws + 128;
        const float* __restrict__ Rf = ws + 640;
        float t0[2], tN[2];
        t0[0] = (float)bp0[TPAD];  tN[0] = (float)bp0[TPAD + IMH - 1];
        t0[1] = (float)bp1[TPAD];  tN[1] = (float)bp1[TPAD + IMH - 1];
        #pragma unroll
        for (int n = 0; n < 4; ++n)
            #pragma unroll
            for (int r = 0; r < 4; ++r) {
                const int row = r0p + 16 * n + 4 * g + r;   // D row = 4g+reg
                const float L = Lf[row], R = Rf[row];
                acc[n][0][r] += L * t0[0] + R * tN[0];
                acc[n][1][r] += L * t0[1] + R * tN[1];
            }
    }

    // store fp32: D col = lane&15 (out col), D row = 4g+reg (out row)
    #pragma unroll
    for (int n = 0; n < 4; ++n)
        #pragma unroll
        for (int r = 0; r < 4; ++r) {
            const size_t ro = (size_t)(r0p + 16 * n + 4 * g + r) * IMW;
            op[ro + cw + ci]      = acc[n][0][r];
            op[ro + cw + 16 + ci] = acc[n][1][r];
        }
}

// ---------------------------------------------------------------------------
extern "C" void kernel_launch(void* const* d_in, const int* in_sizes, int n_in,
                              void* d_out, int out_size, void* d_ws, size_t ws_size,
                              hipStream_t stream) {
    const float* x     = (const float*)d_in[0];
    const float* sigma = (const float*)d_in[1];
    float* out = (float*)d_out;

    // ws: taps/L/R fp32 [0,4608) bytes, fp16 band tables [4608,14848),
    // fp16 tmp^T (24 planes x 512 cols x TK entries) at byte 16384.
    float* ws_f = (float*)d_ws;
    _Float16* tmpT = (_Float16*)((char*)d_ws + 16384);

    weights_kernel<<<1, 128, 0, stream>>>(sigma, ws_f);
    hblur_mfma<<<(NROWS / 128) * (IMW / 64), 256, 0, stream>>>(x, ws_f, tmpT);
    vblur_mfma<<<(NROWS / 64) * (IMW / 128), 256, 0, stream>>>(tmpT, ws_f, out);
}